// Round 3
// baseline (413.645 us; speedup 1.0000x reference)
//
#include <hip/hip_runtime.h>

// Cost volume: out[n,c,d,h,w] = left[n,c,h,w] * right[n,c,h,w-d] (w>=d else 0)
// N=2 C=32 H=136 W=240 D=48. Output 401 MB fp32 -> write-BW bound.
// Output layout is N,C,D,H,W (D *before* H) — round-2 bug was writing N,C,H,D,W.
// grid = (H, N*C); one block per (nc,h) row pair; stage rows in LDS; right row
// is left-padded with D zeros so w<d falls out of the multiply with no branch.

constexpr int W   = 240;
constexpr int H   = 136;
constexpr int D   = 48;
constexpr int W4  = W / 4;        // 60 float4 per row
constexpr int DW4 = D * W4;       // 2880 float4 outputs per block

typedef float v4f __attribute__((ext_vector_type(4)));  // native vec: ok for nontemporal builtin

__global__ __launch_bounds__(256) void cost_volume_kernel(
    const float* __restrict__ left,
    const float* __restrict__ right,
    float* __restrict__ out)
{
    __shared__ float sL[W];
    __shared__ float sR[D + W];   // first D entries are zero padding

    const int h   = blockIdx.x;   // 0..H-1
    const int nc  = blockIdx.y;   // 0..N*C-1
    const int tid = threadIdx.x;
    const size_t row = (size_t)(nc * H + h) * W;   // input row offset

    // Stage: tid [0,60) loads left row, [64,76) zeroes the pad,
    // [128,188) loads right row. All 16B vector ops.
    if (tid < W4) {
        reinterpret_cast<v4f*>(sL)[tid] =
            reinterpret_cast<const v4f*>(left + row)[tid];
    } else if (tid >= 64 && tid < 64 + D / 4) {
        reinterpret_cast<v4f*>(sR)[tid - 64] = (v4f){0.f, 0.f, 0.f, 0.f};
    } else if (tid >= 128 && tid < 128 + W4) {
        reinterpret_cast<v4f*>(sR + D)[tid - 128] =
            reinterpret_cast<const v4f*>(right + row)[tid - 128];
    }
    __syncthreads();

    // out base for (nc, d=0, h): ((nc*D + 0)*H + h)*W ; each d adds H*W.
    v4f* out4 = reinterpret_cast<v4f*>(out) + ((size_t)nc * D * H + h) * W4 * 1;
    // careful: base in float4 units = ((nc*D)*H + h) * W4
    out4 = reinterpret_cast<v4f*>(out) + ((size_t)nc * D * H + h) * (size_t)W4;
    const size_t dstride4 = (size_t)H * W4;        // float4 stride between d-planes
    const float* rpad = sR + D;                    // rpad[w-d] valid for w-d >= -D

    #pragma unroll 2
    for (int i = tid; i < DW4; i += 256) {
        const int d  = i / W4;            // magic-mul division
        const int w4 = i - d * W4;
        const int w  = w4 * 4;
        const v4f l = reinterpret_cast<const v4f*>(sL)[w4];
        v4f v;
        v.x = l.x * rpad[w + 0 - d];
        v.y = l.y * rpad[w + 1 - d];
        v.z = l.z * rpad[w + 2 - d];
        v.w = l.w * rpad[w + 3 - d];
        __builtin_nontemporal_store(v, &out4[(size_t)d * dstride4 + w4]);
    }
}

extern "C" void kernel_launch(void* const* d_in, const int* in_sizes, int n_in,
                              void* d_out, int out_size, void* d_ws, size_t ws_size,
                              hipStream_t stream) {
    const float* left  = (const float*)d_in[0];
    const float* right = (const float*)d_in[1];
    float* out = (float*)d_out;
    const int rows = in_sizes[0] / W;   // N*C*H = 8704
    const int nc   = rows / H;          // N*C = 64
    dim3 grid(H, nc);
    cost_volume_kernel<<<grid, 256, 0, stream>>>(left, right, out);
}